// Round 5
// baseline (116.984 us; speedup 1.0000x reference)
//
#include <hip/hip_runtime.h>
#include <math.h>

#define NN 2048
#define EE 1024

typedef unsigned long long ull;

__device__ __forceinline__ float wave_reduce_sum(float v) {
  #pragma unroll
  for (int o = 32; o > 0; o >>= 1) v += __shfl_xor(v, o, 64);
  return v;
}

// zero NN*EE floats: one float4 per thread, 2048 blocks x 256 threads
__global__ void k_zero(float* __restrict__ p) {
  int i = blockIdx.x * blockDim.x + threadIdx.x;
  *(float4*)&p[(size_t)i * 4] = make_float4(0.f, 0.f, 0.f, 0.f);
}

// dn[n] = deg>0 ? deg^-1/2 : 0, cnt[n] = nnz of row (H binary -> deg == nnz).
__global__ void k_dn(const float* __restrict__ H, float* __restrict__ dn,
                     int* __restrict__ cnt) {
  int wid = (blockIdx.x * blockDim.x + threadIdx.x) >> 6;
  int lane = threadIdx.x & 63;
  const float* row = H + (size_t)wid * EE;
  float s = 0.f;
  #pragma unroll
  for (int i = 0; i < EE; i += 64) s += row[i + lane];
  s = wave_reduce_sum(s);
  if (lane == 0) {
    dn[wid] = s > 0.f ? rsqrtf(s) : 0.f;
    cnt[wid] = (int)(s + 0.5f);
  }
}

// column-sum partials of H: dpart[by][e] = sum over 256 rows
__global__ void k_colsum_part(const float* __restrict__ H, float* __restrict__ dpart) {
  int e = blockIdx.x * 256 + threadIdx.x;
  int r0 = blockIdx.y * 256;
  float s = 0.f;
  #pragma unroll 8
  for (int n = 0; n < 256; ++n) s += H[(size_t)(r0 + n) * EE + e];
  dpart[blockIdx.y * EE + e] = s;
}

__global__ void k_de_fin(const float* __restrict__ dpart, float* __restrict__ de) {
  int e = blockIdx.x * 256 + threadIdx.x;
  float s = 0.f;
  #pragma unroll
  for (int p = 0; p < 8; ++p) s += dpart[p * EE + e];
  de[e] = s > 0.f ? 1.f / s : 0.f;
}

// single-block exclusive scan of cnt[2048] -> roff[2049]
__global__ void k_scan(const int* __restrict__ cnt, int* __restrict__ roff) {
  __shared__ int sc[256];
  int t = threadIdx.x;
  int base = t * 8;
  int v[8];
  int s = 0;
  #pragma unroll
  for (int j = 0; j < 8; ++j) { v[j] = cnt[base + j]; s += v[j]; }
  sc[t] = s;
  __syncthreads();
  for (int off = 1; off < 256; off <<= 1) {
    int a = (t >= off) ? sc[t - off] : 0;
    __syncthreads();
    sc[t] += a;
    __syncthreads();
  }
  int run = sc[t] - s;  // exclusive
  #pragma unroll
  for (int j = 0; j < 8; ++j) { roff[base + j] = run; run += v[j]; }
  if (t == 255) roff[2048] = run;
}

// flat nnz pair list, CSR order: plist[pos] = (n<<16)|e  (deterministic)
__global__ void k_fill(const float* __restrict__ H, const int* __restrict__ roff,
                       unsigned int* __restrict__ plist) {
  int n = (blockIdx.x * blockDim.x + threadIdx.x) >> 6;
  int lane = threadIdx.x & 63;
  const float* row = H + (size_t)n * EE;
  int base = roff[n];
  for (int i = 0; i < EE; i += 64) {
    float hv = row[i + lane];
    ull m = __ballot(hv != 0.f);
    int pos = base + __popcll(m & ((1ull << lane) - 1ull));
    if (hv != 0.f) plist[pos] = ((unsigned int)n << 16) | (unsigned int)(i + lane);
    base += __popcll(m);
  }
}

// pair-parallel scores: 4 lanes per nnz pair, each lane covers 32 of 128 h.
// Mmat (pre-zeroed) gets sigmoid(score) at nnz positions.
__global__ void k_pscore(const float* __restrict__ npb, const float* __restrict__ epb,
                         const float* __restrict__ W2, const float* __restrict__ b2,
                         const int* __restrict__ roff,
                         const unsigned int* __restrict__ plist,
                         float* __restrict__ Mmat) {
  int gid = blockIdx.x * blockDim.x + threadIdx.x;
  int sub = gid & 3;
  int slot = gid >> 2;
  int total = roff[NN];
  float4 w2r[8];
  #pragma unroll
  for (int j = 0; j < 8; ++j) w2r[j] = *(const float4*)&W2[j * 16 + sub * 4];
  float b2v = b2[0];
  int nslots = (gridDim.x * blockDim.x) >> 2;
  for (int p = slot; p < total; p += nslots) {
    unsigned int pk = plist[p];
    int n = pk >> 16, e = pk & 0xFFFF;
    const float* npr = npb + (size_t)n * 128;
    const float* epr = epb + (size_t)e * 128;
    float acc = 0.f;
    #pragma unroll
    for (int j = 0; j < 8; ++j) {
      float4 a = *(const float4*)&npr[j * 16 + sub * 4];
      float4 c = *(const float4*)&epr[j * 16 + sub * 4];
      acc += fmaxf(a.x + c.x, 0.f) * w2r[j].x + fmaxf(a.y + c.y, 0.f) * w2r[j].y
           + fmaxf(a.z + c.z, 0.f) * w2r[j].z + fmaxf(a.w + c.w, 0.f) * w2r[j].w;
    }
    acc += __shfl_xor(acc, 1, 64);
    acc += __shfl_xor(acc, 2, 64);
    if (sub == 0)
      Mmat[(size_t)n * EE + e] = 1.f / (1.f + __expf(-(acc + b2v)));
  }
}

// out[r][h] = (addb ? b1[h] : 0) + sum_d in[r][d] * W1[h][woff+d]
__global__ void k_lin(const float* __restrict__ in, const float* __restrict__ W1,
                      const float* __restrict__ b1, float* __restrict__ out,
                      int woff, int addb) {
  __shared__ float Wl[128 * 65];
  __shared__ float xl[2][64];
  int t = threadIdx.x;
  for (int j = t; j < 128 * 64; j += 256) {
    int h = j >> 6, d = j & 63;
    Wl[h * 65 + d] = W1[h * 128 + woff + d];
  }
  int r0 = blockIdx.x * 2;
  if (t < 128) xl[t >> 6][t & 63] = in[(size_t)(r0 + (t >> 6)) * 64 + (t & 63)];
  __syncthreads();
  int rl = t >> 7;
  int h = t & 127;
  float acc = addb ? b1[h] : 0.f;
  #pragma unroll
  for (int d = 0; d < 64; ++d)
    acc += xl[rl][d] * Wl[h * 65 + d];
  out[(size_t)(r0 + rl) * 128 + h] = acc;
}

// split-K tiled GEMM: part[kb][m][d] = sum_{k in tile kb} A'[m][k] * sB[k]*B[k][d]
template <bool TRANSA>
__global__ void k_gemm(const float* __restrict__ A, int lda,
                       const float* __restrict__ B, const float* __restrict__ sB,
                       float* __restrict__ part, int Mdim) {
  __shared__ float Al[64 * 68];  // Al[k][m]
  __shared__ float Bl[64 * 68];  // Bl[k][d]
  int t = threadIdx.x;
  int m0 = blockIdx.x * 64, k0 = blockIdx.y * 64;
  #pragma unroll
  for (int p = 0; p < 16; ++p) {
    int idx = t + p * 256;
    int i = idx >> 6, j = idx & 63;
    if (TRANSA) Al[i * 68 + j] = A[(size_t)(k0 + i) * lda + m0 + j];
    else        Al[j * 68 + i] = A[(size_t)(m0 + i) * lda + k0 + j];
  }
  #pragma unroll
  for (int p = 0; p < 16; ++p) {
    int idx = t + p * 256;
    int i = idx >> 6, d = idx & 63;
    float v = B[(size_t)(k0 + i) * 64 + d];
    if (sB) v *= sB[k0 + i];
    Bl[i * 68 + d] = v;
  }
  __syncthreads();
  int me0 = (t & 15) * 4, d0 = (t >> 4) * 4;
  float acc[4][4] = {};
  #pragma unroll 8
  for (int k = 0; k < 64; ++k) {
    float av[4], bv[4];
    *(float4*)av = *(const float4*)&Al[k * 68 + me0];
    *(float4*)bv = *(const float4*)&Bl[k * 68 + d0];
    #pragma unroll
    for (int r = 0; r < 4; ++r)
      #pragma unroll
      for (int c = 0; c < 4; ++c)
        acc[r][c] += av[r] * bv[c];
  }
  float* po = part + (size_t)blockIdx.y * Mdim * 64;
  #pragma unroll
  for (int r = 0; r < 4; ++r)
    *(float4*)&po[(size_t)(m0 + me0 + r) * 64 + d0] = *(float4*)acc[r];
}

// out[m][d] = (smode ? scale[m] : 1) * sum_s part[s][m][d]
__global__ void k_red(const float* __restrict__ part, int S, int Mdim,
                      const float* __restrict__ scale, int smode,
                      float* __restrict__ out) {
  int idx = blockIdx.x * 256 + threadIdx.x;
  float s = 0.f;
  for (int p = 0; p < S; ++p) s += part[(size_t)p * Mdim * 64 + idx];
  if (smode) s *= scale[idx >> 6];
  out[idx] = s;
}

// fused: y[n][d] = dn[n] * sum_{p<16} part[p][n][d];  out = y @ Wl^T + bl
__global__ void k_out(const float* __restrict__ part, const float* __restrict__ dnv,
                      const float* __restrict__ Wlg, const float* __restrict__ bl,
                      float* __restrict__ out) {
  __shared__ float yl[4][64];
  __shared__ float Wlds[64][65];
  int t = threadIdx.x;
  int n0 = blockIdx.x * 4;
  for (int j = t; j < 4096; j += 256) Wlds[j >> 6][j & 63] = Wlg[j];
  {
    int nl = t >> 6, d = t & 63;
    int n = n0 + nl;
    float s = 0.f;
    #pragma unroll
    for (int p = 0; p < 16; ++p) s += part[(size_t)p * NN * 64 + (size_t)n * 64 + d];
    yl[nl][d] = dnv[n] * s;
  }
  __syncthreads();
  int rl = t >> 6, o = t & 63;
  float acc = bl[o];
  #pragma unroll
  for (int d = 0; d < 64; ++d)
    acc += yl[rl][d] * Wlds[o][d];
  out[(size_t)(n0 + rl) * 64 + o] = acc;
}

extern "C" void kernel_launch(void* const* d_in, const int* in_sizes, int n_in,
                              void* d_out, int out_size, void* d_ws, size_t ws_size,
                              hipStream_t stream) {
  const float* x  = (const float*)d_in[0];
  const float* H  = (const float*)d_in[1];
  const float* W1 = (const float*)d_in[2];
  const float* b1 = (const float*)d_in[3];
  const float* W2 = (const float*)d_in[4];
  const float* b2 = (const float*)d_in[5];
  const float* Wl = (const float*)d_in[6];
  const float* bl = (const float*)d_in[7];
  float* out = (float*)d_out;

  char* wsb = (char*)d_ws;
  float* dn    = (float*)wsb;            wsb += NN * 4;
  float* de    = (float*)wsb;            wsb += EE * 4;
  float* dpart = (float*)wsb;            wsb += 8 * EE * 4;
  int*   cnt   = (int*)wsb;              wsb += NN * 4;
  int*   roff  = (int*)wsb;              wsb += (NN + 4) * 4;
  unsigned int* plist = (unsigned int*)wsb; wsb += 512 * 1024 * 4;  // cap 512K nnz (actual ~105K)
  float* npb   = (float*)wsb;            wsb += NN * 128 * 4;
  float* epb   = (float*)wsb;            wsb += EE * 128 * 4;
  float* ef    = (float*)wsb;            wsb += EE * 64 * 4;
  float* w     = (float*)wsb;            wsb += EE * 64 * 4;
  float* Mmat  = (float*)wsb;            wsb += (size_t)NN * EE * 4;
  float* part  = (float*)wsb;            wsb += (size_t)NN * EE * 4;

  // zero the sparse score matrix with our own kernel (rocclr fill was 39 us!)
  hipLaunchKernelGGL(k_zero, dim3(NN * EE / 1024), dim3(256), 0, stream, Mmat);

  // degrees / scalings / sparsity structure
  hipLaunchKernelGGL(k_dn, dim3(NN / 4), dim3(256), 0, stream, H, dn, cnt);
  hipLaunchKernelGGL(k_colsum_part, dim3(EE / 256, 8), dim3(256), 0, stream, H, dpart);
  hipLaunchKernelGGL(k_de_fin, dim3(EE / 256), dim3(256), 0, stream, dpart, de);
  hipLaunchKernelGGL(k_scan, dim3(1), dim3(256), 0, stream, cnt, roff);
  hipLaunchKernelGGL(k_fill, dim3(NN / 4), dim3(256), 0, stream, H, roff, plist);
  // node projection
  hipLaunchKernelGGL(k_lin, dim3(NN / 2), dim3(256), 0, stream, x, W1, b1, npb, 0, 1);
  // ef = H^T @ x
  hipLaunchKernelGGL(k_gemm<true>, dim3(EE / 64, NN / 64), dim3(256), 0, stream,
                     H, EE, x, (const float*)nullptr, part, EE);
  hipLaunchKernelGGL(k_red, dim3(EE * 64 / 256), dim3(256), 0, stream,
                     part, NN / 64, EE, (const float*)nullptr, 0, ef);
  // edge projection
  hipLaunchKernelGGL(k_lin, dim3(EE / 2), dim3(256), 0, stream, ef, W1, b1, epb, 64, 0);
  // pair-parallel masked attention scores
  hipLaunchKernelGGL(k_pscore, dim3(2048), dim3(256), 0, stream,
                     npb, epb, W2, b2, roff, plist, Mmat);
  // t = M^T @ (dn*x);  w = de * t
  hipLaunchKernelGGL(k_gemm<true>, dim3(EE / 64, NN / 64), dim3(256), 0, stream,
                     Mmat, EE, x, dn, part, EE);
  hipLaunchKernelGGL(k_red, dim3(EE * 64 / 256), dim3(256), 0, stream,
                     part, NN / 64, EE, de, 1, w);
  // z = M @ w;  y = dn*z;  out = y @ Wl^T + bl  (reduction fused into k_out)
  hipLaunchKernelGGL(k_gemm<false>, dim3(NN / 64, EE / 64), dim3(256), 0, stream,
                     Mmat, EE, w, (const float*)nullptr, part, NN);
  hipLaunchKernelGGL(k_out, dim3(NN / 4), dim3(256), 0, stream, part, dn, Wl, bl, out);
}

// Round 6
// 100.698 us; speedup vs baseline: 1.1617x; 1.1617x over previous
//
#include <hip/hip_runtime.h>
#include <math.h>

#define NN 2048
#define EE 1024

typedef unsigned long long ull;

// ---------------------------------------------------------------------------
// k_pre: one dispatch, four independent jobs selected by block range.
//   [0,512)    rfill : wave per node row -> elist[n][128], cnt[n], dn[n]
//   [512,768)  cscan : wave per edge col -> clist[e][192], ccnt[e], de[e]
//   [768,1792) npb   : node projection npb = x @ W1[:, :64]^T + b1
//   [1792,2048)gemm  : ef split-K partials: part[s] = H^T[*,ktile] @ x[ktile,*]
// ---------------------------------------------------------------------------
__global__ void k_pre(const float* __restrict__ H, const float* __restrict__ x,
                      const float* __restrict__ W1, const float* __restrict__ b1,
                      unsigned short* __restrict__ elist, int* __restrict__ cnt,
                      float* __restrict__ dn,
                      unsigned short* __restrict__ clist, int* __restrict__ ccnt,
                      float* __restrict__ de,
                      float* __restrict__ npb, float* __restrict__ part) {
  __shared__ __align__(16) char smem[34816];
  int bid = blockIdx.x, t = threadIdx.x;
  if (bid < 512) {
    // ---- rfill: CSR-style padded row lists (ascending e, deterministic)
    int n = bid * 4 + (t >> 6), lane = t & 63;
    const float* row = H + (size_t)n * EE;
    int count = 0;
    for (int i = 0; i < EE; i += 64) {
      float hv = row[i + lane];
      ull m = __ballot(hv != 0.f);
      int pos = count + __popcll(m & ((1ull << lane) - 1ull));
      if (hv != 0.f && pos < 128) elist[n * 128 + pos] = (unsigned short)(i + lane);
      count += __popcll(m);
    }
    if (lane == 0) {
      cnt[n] = count;
      dn[n] = count ? rsqrtf((float)count) : 0.f;
    }
  } else if (bid < 768) {
    // ---- cscan: CSC-style padded column lists (ascending n, deterministic)
    int e = (bid - 512) * 4 + (t >> 6), lane = t & 63;
    int count = 0;
    for (int i = 0; i < NN; i += 64) {
      float hv = H[(size_t)(i + lane) * EE + e];
      ull m = __ballot(hv != 0.f);
      int pos = count + __popcll(m & ((1ull << lane) - 1ull));
      if (hv != 0.f && pos < 192) clist[e * 192 + pos] = (unsigned short)(i + lane);
      count += __popcll(m);
    }
    if (lane == 0) {
      ccnt[e] = count;
      de[e] = count ? 1.f / (float)count : 0.f;
    }
  } else if (bid < 1792) {
    // ---- node projection: 2 rows x 128 h per block, W1 node-half in LDS
    float* Wl = (float*)smem;       // 128*65
    float* xl = Wl + 128 * 65;      // 2*64
    int b = bid - 768;
    for (int j = t; j < 128 * 64; j += 256) {
      int h = j >> 6, d = j & 63;
      Wl[h * 65 + d] = W1[h * 128 + d];
    }
    int r0 = b * 2;
    if (t < 128) xl[(t >> 6) * 64 + (t & 63)] = x[(size_t)(r0 + (t >> 6)) * 64 + (t & 63)];
    __syncthreads();
    int rl = t >> 7, h = t & 127;
    float acc = b1[h];
    #pragma unroll
    for (int d = 0; d < 64; ++d)
      acc += xl[rl * 64 + d] * Wl[h * 65 + d];
    npb[(size_t)(r0 + rl) * 128 + h] = acc;
  } else {
    // ---- ef GEMM partials: M=EE tile 64, K-tile 128 (2 subtiles of 64)
    float* Al = (float*)smem;       // 64*68  [k][m]
    float* Bl = Al + 64 * 68;       // 64*68  [k][d]
    int b = bid - 1792;
    int m0 = (b & 15) * 64, s = b >> 4, k0 = s * 128;
    int me0 = (t & 15) * 4, d0 = (t >> 4) * 4;
    float acc[4][4] = {};
    for (int sub = 0; sub < 2; ++sub) {
      int k0s = k0 + sub * 64;
      if (sub) __syncthreads();
      #pragma unroll
      for (int p = 0; p < 16; ++p) {
        int idx = t + p * 256;
        int i = idx >> 6, j = idx & 63;
        Al[i * 68 + j] = H[(size_t)(k0s + i) * EE + m0 + j];
      }
      #pragma unroll
      for (int p = 0; p < 16; ++p) {
        int idx = t + p * 256;
        int i = idx >> 6, d = idx & 63;
        Bl[i * 68 + d] = x[(size_t)(k0s + i) * 64 + d];
      }
      __syncthreads();
      #pragma unroll 8
      for (int k = 0; k < 64; ++k) {
        float av[4], bv[4];
        *(float4*)av = *(const float4*)&Al[k * 68 + me0];
        *(float4*)bv = *(const float4*)&Bl[k * 68 + d0];
        #pragma unroll
        for (int r = 0; r < 4; ++r)
          #pragma unroll
          for (int c = 0; c < 4; ++c)
            acc[r][c] += av[r] * bv[c];
      }
    }
    float* po = part + (size_t)s * EE * 64;
    #pragma unroll
    for (int r = 0; r < 4; ++r)
      *(float4*)&po[(size_t)(m0 + me0 + r) * 64 + d0] = *(float4*)acc[r];
  }
}

// ---------------------------------------------------------------------------
// k_epb: epb[e][h] = (sum_s part[s][e][*]) @ W1[:,64:128]^T   (no bias)
// ---------------------------------------------------------------------------
__global__ void k_epb(const float* __restrict__ part, const float* __restrict__ W1,
                      float* __restrict__ epb) {
  __shared__ float Wl[128 * 65];
  __shared__ float xl[2][64];
  int t = threadIdx.x;
  for (int j = t; j < 128 * 64; j += 256) {
    int h = j >> 6, d = j & 63;
    Wl[h * 65 + d] = W1[h * 128 + 64 + d];
  }
  int r0 = blockIdx.x * 2;
  if (t < 128) {
    int r = t >> 6, d = t & 63;
    float s = 0.f;
    #pragma unroll
    for (int p = 0; p < 16; ++p)
      s += part[(size_t)p * EE * 64 + (size_t)(r0 + r) * 64 + d];
    xl[r][d] = s;
  }
  __syncthreads();
  int rl = t >> 7, h = t & 127;
  float acc = 0.f;
  #pragma unroll
  for (int d = 0; d < 64; ++d)
    acc += xl[rl][d] * Wl[h * 65 + d];
  epb[(size_t)(r0 + rl) * 128 + h] = acc;
}

// ---------------------------------------------------------------------------
// k_pscore: padded row slots, 4 lanes per slot (each lane 32 of 128 h).
// writes sigmoid to sval[n][j] (row-padded) and Mmat[n][e] (scattered; Mmat
// is only ever read back at these same nnz positions -> no zeroing needed).
// ---------------------------------------------------------------------------
__global__ void k_pscore(const float* __restrict__ npb, const float* __restrict__ epb,
                         const float* __restrict__ W2, const float* __restrict__ b2,
                         const int* __restrict__ cnt,
                         const unsigned short* __restrict__ elist,
                         float* __restrict__ sval, float* __restrict__ Mmat) {
  int gid = blockIdx.x * blockDim.x + threadIdx.x;
  int sub = gid & 3;
  int slot = gid >> 2;           // 0 .. NN*128-1
  int n = slot >> 7, j = slot & 127;
  int c = min(cnt[n], 128);
  if (j >= c) return;
  int e = elist[n * 128 + j];
  const float* npr = npb + (size_t)n * 128;
  const float* epr = epb + (size_t)e * 128;
  float acc = 0.f;
  #pragma unroll
  for (int q = 0; q < 8; ++q) {
    float4 a = *(const float4*)&npr[q * 16 + sub * 4];
    float4 cc = *(const float4*)&epr[q * 16 + sub * 4];
    float4 w2 = *(const float4*)&W2[q * 16 + sub * 4];
    acc += fmaxf(a.x + cc.x, 0.f) * w2.x + fmaxf(a.y + cc.y, 0.f) * w2.y
         + fmaxf(a.z + cc.z, 0.f) * w2.z + fmaxf(a.w + cc.w, 0.f) * w2.w;
  }
  acc += __shfl_xor(acc, 1, 64);
  acc += __shfl_xor(acc, 2, 64);
  if (sub == 0) {
    float s = 1.f / (1.f + __expf(-(acc + b2[0])));
    sval[slot] = s;
    Mmat[(size_t)n * EE + e] = s;
  }
}

// ---------------------------------------------------------------------------
// k_w: w[e][d] = de[e] * sum_{j<ccnt[e]} sig(n_j,e) * dn[n_j] * x[n_j][d]
// 2 waves per edge (even/odd j), LDS combine.
// ---------------------------------------------------------------------------
__global__ void k_w(const unsigned short* __restrict__ clist, const int* __restrict__ ccnt,
                    const float* __restrict__ de, const float* __restrict__ dn,
                    const float* __restrict__ x, const float* __restrict__ Mmat,
                    float* __restrict__ w) {
  __shared__ float psum[4][64];
  int t = threadIdx.x, wv = t >> 6, lane = t & 63;
  int e = blockIdx.x * 2 + (wv >> 1), sub = wv & 1;
  int c = min(ccnt[e], 192);
  float acc = 0.f;
  for (int j = sub; j < c; j += 2) {
    int n = clist[e * 192 + j];
    float sg = Mmat[(size_t)n * EE + e];
    acc += sg * dn[n] * x[(size_t)n * 64 + lane];
  }
  psum[wv][lane] = acc;
  __syncthreads();
  if (sub == 0)
    w[(size_t)e * 64 + lane] = de[e] * (psum[wv][lane] + psum[wv + 1][lane]);
}

// ---------------------------------------------------------------------------
// k_zout: y[n][d] = dn[n] * sum_{j<cnt[n]} sval[n][j] * w[e_j][d];
//         out[n][o] = y[n] . Wl[o] + bl[o]   (final linear fused)
// wave per node; Wl + bl staged in LDS per block.
// ---------------------------------------------------------------------------
__global__ void k_zout(const unsigned short* __restrict__ elist, const int* __restrict__ cnt,
                       const float* __restrict__ dn, const float* __restrict__ sval,
                       const float* __restrict__ w, const float* __restrict__ Wlg,
                       const float* __restrict__ bl, float* __restrict__ out) {
  __shared__ float Wlds[64 * 65];
  __shared__ float zl[4][64];
  __shared__ float blds[64];
  int t = threadIdx.x, wv = t >> 6, lane = t & 63;
  for (int j = t; j < 4096; j += 256)
    Wlds[(j >> 6) * 65 + (j & 63)] = Wlg[j];
  if (t < 64) blds[t] = bl[t];
  int n = blockIdx.x * 4 + wv;
  int c = min(cnt[n], 128);
  float acc = 0.f;
  for (int j = 0; j < c; ++j) {
    float sv = sval[n * 128 + j];
    int e = elist[n * 128 + j];
    acc += sv * w[(size_t)e * 64 + lane];
  }
  zl[wv][lane] = dn[n] * acc;
  __syncthreads();
  float o = blds[lane];
  #pragma unroll
  for (int d = 0; d < 64; ++d)
    o += zl[wv][d] * Wlds[lane * 65 + d];
  out[(size_t)n * 64 + lane] = o;
}

extern "C" void kernel_launch(void* const* d_in, const int* in_sizes, int n_in,
                              void* d_out, int out_size, void* d_ws, size_t ws_size,
                              hipStream_t stream) {
  const float* x  = (const float*)d_in[0];
  const float* H  = (const float*)d_in[1];
  const float* W1 = (const float*)d_in[2];
  const float* b1 = (const float*)d_in[3];
  const float* W2 = (const float*)d_in[4];
  const float* b2 = (const float*)d_in[5];
  const float* Wl = (const float*)d_in[6];
  const float* bl = (const float*)d_in[7];
  float* out = (float*)d_out;

  char* wsb = (char*)d_ws;
  float* dn    = (float*)wsb;  wsb += NN * 4;
  float* de    = (float*)wsb;  wsb += EE * 4;
  int*   cnt   = (int*)wsb;    wsb += NN * 4;
  int*   ccnt  = (int*)wsb;    wsb += EE * 4;
  float* npb   = (float*)wsb;  wsb += (size_t)NN * 128 * 4;
  float* epb   = (float*)wsb;  wsb += (size_t)EE * 128 * 4;
  float* part  = (float*)wsb;  wsb += (size_t)16 * EE * 64 * 4;
  float* sval  = (float*)wsb;  wsb += (size_t)NN * 128 * 4;
  float* Mmat  = (float*)wsb;  wsb += (size_t)NN * EE * 4;
  float* w     = (float*)wsb;  wsb += (size_t)EE * 64 * 4;
  unsigned short* elist = (unsigned short*)wsb; wsb += (size_t)NN * 128 * 2;
  unsigned short* clist = (unsigned short*)wsb; wsb += (size_t)EE * 192 * 2;

  // D1: structure + degrees + node projection + ef GEMM partials (fused)
  hipLaunchKernelGGL(k_pre, dim3(2048), dim3(256), 0, stream,
                     H, x, W1, b1, elist, cnt, dn, clist, ccnt, de, npb, part);
  // D2: edge projection (ef reduction fused)
  hipLaunchKernelGGL(k_epb, dim3(EE / 2), dim3(256), 0, stream, part, W1, epb);
  // D3: sparse attention scores -> sval (row-padded) + Mmat (scattered)
  hipLaunchKernelGGL(k_pscore, dim3(NN * 128 * 4 / 256), dim3(256), 0, stream,
                     npb, epb, W2, b2, cnt, elist, sval, Mmat);
  // D4: w = de * (M^T @ (dn*x))  via column lists
  hipLaunchKernelGGL(k_w, dim3(EE / 2), dim3(256), 0, stream,
                     clist, ccnt, de, dn, x, Mmat, w);
  // D5: y = dn * (M @ w);  out = y @ Wl^T + bl  via row lists (fused final)
  hipLaunchKernelGGL(k_zout, dim3(NN / 4), dim3(256), 0, stream,
                     elist, cnt, dn, sval, w, Wl, bl, out);
}

// Round 7
// 70.967 us; speedup vs baseline: 1.6484x; 1.4190x over previous
//
#include <hip/hip_runtime.h>
#include <math.h>

#define NN 2048
#define EE 1024

typedef unsigned long long ull;

// ---------------------------------------------------------------------------
// k_pre: one dispatch, four independent jobs selected by block range.
//   [0,512)    rfill : wave per node row -> elist[n][128], cnt[n], dn[n]
//   [512,768)  cscan : wave per edge col -> clist[e][192], ccnt[e], de[e]
//   [768,1792) npb   : node projection npb = x @ W1[:, :64]^T + b1
//   [1792,2048)gemm  : ef split-K partials: part[s] = H^T[*,ktile] @ x[ktile,*]
// ---------------------------------------------------------------------------
__global__ void k_pre(const float* __restrict__ H, const float* __restrict__ x,
                      const float* __restrict__ W1, const float* __restrict__ b1,
                      unsigned short* __restrict__ elist, int* __restrict__ cnt,
                      float* __restrict__ dn,
                      unsigned short* __restrict__ clist, int* __restrict__ ccnt,
                      float* __restrict__ de,
                      float* __restrict__ npb, float* __restrict__ part) {
  __shared__ __align__(16) char smem[34816];
  int bid = blockIdx.x, t = threadIdx.x;
  if (bid < 512) {
    // ---- rfill: CSR-style padded row lists (ascending e, deterministic)
    int n = bid * 4 + (t >> 6), lane = t & 63;
    const float* row = H + (size_t)n * EE;
    int count = 0;
    for (int i = 0; i < EE; i += 64) {
      float hv = row[i + lane];
      ull m = __ballot(hv != 0.f);
      int pos = count + __popcll(m & ((1ull << lane) - 1ull));
      if (hv != 0.f && pos < 128) elist[n * 128 + pos] = (unsigned short)(i + lane);
      count += __popcll(m);
    }
    if (lane == 0) {
      cnt[n] = count;
      dn[n] = count ? rsqrtf((float)count) : 0.f;
    }
  } else if (bid < 768) {
    // ---- cscan: CSC-style padded column lists (ascending n, deterministic)
    int e = (bid - 512) * 4 + (t >> 6), lane = t & 63;
    int count = 0;
    for (int i = 0; i < NN; i += 64) {
      float hv = H[(size_t)(i + lane) * EE + e];
      ull m = __ballot(hv != 0.f);
      int pos = count + __popcll(m & ((1ull << lane) - 1ull));
      if (hv != 0.f && pos < 192) clist[e * 192 + pos] = (unsigned short)(i + lane);
      count += __popcll(m);
    }
    if (lane == 0) {
      ccnt[e] = count;
      de[e] = count ? 1.f / (float)count : 0.f;
    }
  } else if (bid < 1792) {
    // ---- node projection: 2 rows x 128 h per block, W1 node-half in LDS
    float* Wl = (float*)smem;       // 128*65
    float* xl = Wl + 128 * 65;      // 2*64
    int b = bid - 768;
    for (int j = t; j < 128 * 64; j += 256) {
      int h = j >> 6, d = j & 63;
      Wl[h * 65 + d] = W1[h * 128 + d];
    }
    int r0 = b * 2;
    if (t < 128) xl[(t >> 6) * 64 + (t & 63)] = x[(size_t)(r0 + (t >> 6)) * 64 + (t & 63)];
    __syncthreads();
    int rl = t >> 7, h = t & 127;
    float acc = b1[h];
    #pragma unroll
    for (int d = 0; d < 64; ++d)
      acc += xl[rl * 64 + d] * Wl[h * 65 + d];
    npb[(size_t)(r0 + rl) * 128 + h] = acc;
  } else {
    // ---- ef GEMM partials: M=EE tile 64, K-tile 128 (2 subtiles of 64)
    float* Al = (float*)smem;       // 64*68  [k][m]
    float* Bl = Al + 64 * 68;       // 64*68  [k][d]
    int b = bid - 1792;
    int m0 = (b & 15) * 64, s = b >> 4, k0 = s * 128;
    int me0 = (t & 15) * 4, d0 = (t >> 4) * 4;
    float acc[4][4] = {};
    for (int sub = 0; sub < 2; ++sub) {
      int k0s = k0 + sub * 64;
      if (sub) __syncthreads();
      #pragma unroll
      for (int p = 0; p < 16; ++p) {
        int idx = t + p * 256;
        int i = idx >> 6, j = idx & 63;
        Al[i * 68 + j] = H[(size_t)(k0s + i) * EE + m0 + j];
      }
      #pragma unroll
      for (int p = 0; p < 16; ++p) {
        int idx = t + p * 256;
        int i = idx >> 6, d = idx & 63;
        Bl[i * 68 + d] = x[(size_t)(k0s + i) * 64 + d];
      }
      __syncthreads();
      #pragma unroll 8
      for (int k = 0; k < 64; ++k) {
        float av[4], bv[4];
        *(float4*)av = *(const float4*)&Al[k * 68 + me0];
        *(float4*)bv = *(const float4*)&Bl[k * 68 + d0];
        #pragma unroll
        for (int r = 0; r < 4; ++r)
          #pragma unroll
          for (int c = 0; c < 4; ++c)
            acc[r][c] += av[r] * bv[c];
      }
    }
    float* po = part + (size_t)s * EE * 64;
    #pragma unroll
    for (int r = 0; r < 4; ++r)
      *(float4*)&po[(size_t)(m0 + me0 + r) * 64 + d0] = *(float4*)acc[r];
  }
}

// ---------------------------------------------------------------------------
// k_epb: epb[e][h] = (sum_s part[s][e][*]) @ W1[:,64:128]^T   (no bias)
// ---------------------------------------------------------------------------
__global__ void k_epb(const float* __restrict__ part, const float* __restrict__ W1,
                      float* __restrict__ epb) {
  __shared__ float Wl[128 * 65];
  __shared__ float xl[2][64];
  int t = threadIdx.x;
  for (int j = t; j < 128 * 64; j += 256) {
    int h = j >> 6, d = j & 63;
    Wl[h * 65 + d] = W1[h * 128 + 64 + d];
  }
  int r0 = blockIdx.x * 2;
  if (t < 128) {
    int r = t >> 6, d = t & 63;
    float s = 0.f;
    #pragma unroll
    for (int p = 0; p < 16; ++p)
      s += part[(size_t)p * EE * 64 + (size_t)(r0 + r) * 64 + d];
    xl[r][d] = s;
  }
  __syncthreads();
  int rl = t >> 7, h = t & 127;
  float acc = 0.f;
  #pragma unroll
  for (int d = 0; d < 64; ++d)
    acc += xl[rl][d] * Wl[h * 65 + d];
  epb[(size_t)(r0 + rl) * 128 + h] = acc;
}

// ---------------------------------------------------------------------------
// k_pscore: scores computed in BOTH orderings (27 MFLOP each, cheap).
//   slots [0, NN*128)            : row-padded -> sval_r[n][j] = sigmoid
//   slots [NN*128, +EE*192)      : col-padded -> sval_c[e][j] = sigmoid * dn[n]
// 4 lanes per slot (each lane covers 32 of 128 h), 2-step shfl reduce.
// No scattered Mmat buffer, no zeroing -- all downstream reads are sequential.
// ---------------------------------------------------------------------------
__global__ void k_pscore(const float* __restrict__ npb, const float* __restrict__ epb,
                         const float* __restrict__ W2, const float* __restrict__ b2,
                         const int* __restrict__ cnt, const unsigned short* __restrict__ elist,
                         const int* __restrict__ ccnt, const unsigned short* __restrict__ clist,
                         const float* __restrict__ dn,
                         float* __restrict__ sval_r, float* __restrict__ sval_c) {
  int gid = blockIdx.x * blockDim.x + threadIdx.x;
  int sub = gid & 3;
  int slot = gid >> 2;
  int n, e;
  float scale;
  float* dst;
  if (slot < NN * 128) {
    n = slot >> 7;
    int j = slot & 127;
    if (j >= min(cnt[n], 128)) return;
    e = elist[slot];
    scale = 1.f;
    dst = sval_r + slot;
  } else {
    int cs = slot - NN * 128;
    e = cs / 192;
    int j = cs - e * 192;
    if (j >= min(ccnt[e], 192)) return;
    n = clist[cs];
    scale = dn[n];
    dst = sval_c + cs;
  }
  const float* npr = npb + (size_t)n * 128;
  const float* epr = epb + (size_t)e * 128;
  float acc = 0.f;
  #pragma unroll
  for (int q = 0; q < 8; ++q) {
    float4 a = *(const float4*)&npr[q * 16 + sub * 4];
    float4 c = *(const float4*)&epr[q * 16 + sub * 4];
    float4 w2 = *(const float4*)&W2[q * 16 + sub * 4];
    acc += fmaxf(a.x + c.x, 0.f) * w2.x + fmaxf(a.y + c.y, 0.f) * w2.y
         + fmaxf(a.z + c.z, 0.f) * w2.z + fmaxf(a.w + c.w, 0.f) * w2.w;
  }
  acc += __shfl_xor(acc, 1, 64);
  acc += __shfl_xor(acc, 2, 64);
  if (sub == 0)
    *dst = scale / (1.f + __expf(-(acc + b2[0])));
}

// ---------------------------------------------------------------------------
// k_w: w[e][d] = de[e] * sum_j sval_c[e][j] * x[n_j][d]
// one block (4 waves) per edge; j strided by wave; LDS combine.
// coefficients read sequentially (L1); x rows coalesced (x is L2-resident).
// ---------------------------------------------------------------------------
__global__ void k_w(const unsigned short* __restrict__ clist, const int* __restrict__ ccnt,
                    const float* __restrict__ de, const float* __restrict__ sval_c,
                    const float* __restrict__ x, float* __restrict__ w) {
  __shared__ float psum[4][64];
  int t = threadIdx.x, wv = t >> 6, lane = t & 63;
  int e = blockIdx.x;
  int c = min(ccnt[e], 192);
  float acc = 0.f;
  for (int j = wv; j < c; j += 4) {
    int n = clist[e * 192 + j];
    acc += sval_c[e * 192 + j] * x[(size_t)n * 64 + lane];
  }
  psum[wv][lane] = acc;
  __syncthreads();
  if (wv == 0)
    w[(size_t)e * 64 + lane] =
        de[e] * (psum[0][lane] + psum[1][lane] + psum[2][lane] + psum[3][lane]);
}

// ---------------------------------------------------------------------------
// k_zout: z[d] = dn[n] * sum_j sval_r[n][j] * w[e_j][d];  out[n] = z @ Wl^T + bl
// one block (4 waves) per node; gather j strided by wave; final 64x64 linear
// distributed across waves (each wave covers a 16-wide d-slice).
// ---------------------------------------------------------------------------
__global__ void k_zout(const unsigned short* __restrict__ elist, const int* __restrict__ cnt,
                       const float* __restrict__ dn, const float* __restrict__ sval_r,
                       const float* __restrict__ w, const float* __restrict__ Wlg,
                       const float* __restrict__ bl, float* __restrict__ out) {
  __shared__ float Wlds[64 * 65];
  __shared__ float psum[4][64];
  __shared__ float zl[64];
  int t = threadIdx.x, wv = t >> 6, lane = t & 63;
  int n = blockIdx.x;
  for (int j = t; j < 4096; j += 256)
    Wlds[(j >> 6) * 65 + (j & 63)] = Wlg[j];
  int c = min(cnt[n], 128);
  float acc = 0.f;
  for (int j = wv; j < c; j += 4) {
    int e = elist[n * 128 + j];
    acc += sval_r[n * 128 + j] * w[(size_t)e * 64 + lane];
  }
  psum[wv][lane] = acc;
  __syncthreads();
  if (wv == 0)
    zl[lane] = dn[n] * (psum[0][lane] + psum[1][lane] + psum[2][lane] + psum[3][lane]);
  __syncthreads();
  // partial matvec: wave wv covers d in [wv*16, wv*16+16)
  float po = 0.f;
  #pragma unroll
  for (int d = 0; d < 16; ++d)
    po += zl[wv * 16 + d] * Wlds[lane * 65 + wv * 16 + d];
  psum[wv][lane] = po;
  __syncthreads();
  if (wv == 0)
    out[(size_t)n * 64 + lane] =
        bl[lane] + psum[0][lane] + psum[1][lane] + psum[2][lane] + psum[3][lane];
}

extern "C" void kernel_launch(void* const* d_in, const int* in_sizes, int n_in,
                              void* d_out, int out_size, void* d_ws, size_t ws_size,
                              hipStream_t stream) {
  const float* x  = (const float*)d_in[0];
  const float* H  = (const float*)d_in[1];
  const float* W1 = (const float*)d_in[2];
  const float* b1 = (const float*)d_in[3];
  const float* W2 = (const float*)d_in[4];
  const float* b2 = (const float*)d_in[5];
  const float* Wl = (const float*)d_in[6];
  const float* bl = (const float*)d_in[7];
  float* out = (float*)d_out;

  char* wsb = (char*)d_ws;
  float* dn     = (float*)wsb;  wsb += NN * 4;
  float* de     = (float*)wsb;  wsb += EE * 4;
  int*   cnt    = (int*)wsb;    wsb += NN * 4;
  int*   ccnt   = (int*)wsb;    wsb += EE * 4;
  float* npb    = (float*)wsb;  wsb += (size_t)NN * 128 * 4;
  float* epb    = (float*)wsb;  wsb += (size_t)EE * 128 * 4;
  float* part   = (float*)wsb;  wsb += (size_t)16 * EE * 64 * 4;
  float* sval_r = (float*)wsb;  wsb += (size_t)NN * 128 * 4;
  float* sval_c = (float*)wsb;  wsb += (size_t)EE * 192 * 4;
  float* w      = (float*)wsb;  wsb += (size_t)EE * 64 * 4;
  unsigned short* elist = (unsigned short*)wsb; wsb += (size_t)NN * 128 * 2;
  unsigned short* clist = (unsigned short*)wsb; wsb += (size_t)EE * 192 * 2;

  // D1: structure + degrees + node projection + ef GEMM partials (fused)
  hipLaunchKernelGGL(k_pre, dim3(2048), dim3(256), 0, stream,
                     H, x, W1, b1, elist, cnt, dn, clist, ccnt, de, npb, part);
  // D2: edge projection (ef reduction fused)
  hipLaunchKernelGGL(k_epb, dim3(EE / 2), dim3(256), 0, stream, part, W1, epb);
  // D3: sparse attention scores in both orderings (no scatter, no zeroing)
  hipLaunchKernelGGL(k_pscore, dim3((NN * 128 + EE * 192) * 4 / 256), dim3(256), 0, stream,
                     npb, epb, W2, b2, cnt, elist, ccnt, clist, dn, sval_r, sval_c);
  // D4: w = de * (M^T @ (dn*x))  via CSC lists, sequential coefficients
  hipLaunchKernelGGL(k_w, dim3(EE), dim3(256), 0, stream,
                     clist, ccnt, de, sval_c, x, w);
  // D5: z = dn * (M @ w); out = z @ Wl^T + bl  via CSR lists (fused final)
  hipLaunchKernelGGL(k_zout, dim3(NN), dim3(256), 0, stream,
                     elist, cnt, dn, sval_r, w, Wl, bl, out);
}